// Round 1
// baseline (378.456 us; speedup 1.0000x reference)
//
#include <hip/hip_runtime.h>
#include <stdint.h>

typedef short short8 __attribute__((ext_vector_type(8)));
typedef float f32x4 __attribute__((ext_vector_type(4)));

#define LOG2E 1.44269504088896f

__device__ __forceinline__ unsigned short f2b(float f) {
  union { float f; unsigned int u; } x; x.f = f;
  unsigned int u = x.u;
  unsigned int r = (u + 0x7fffu + ((u >> 16) & 1u)) >> 16;
  return (unsigned short)r;
}
__device__ __forceinline__ float b2f(unsigned short s) {
  union { unsigned int u; float f; } x; x.u = ((unsigned int)s) << 16;
  return x.f;
}
__device__ __forceinline__ void gl16(const void* g, void* l) {
  __builtin_amdgcn_global_load_lds((const __attribute__((address_space(1))) void*)g,
                                   (__attribute__((address_space(3))) void*)l, 16, 0, 0);
}

// ---------------- cast x -> bf16 ----------------
__global__ __launch_bounds__(256) void castx_k(const float* __restrict__ X,
                                               unsigned short* __restrict__ Xb) {
  int i = blockIdx.x * 256 + threadIdx.x;  // one thread = 8 elems
  const float* p = X + (size_t)i * 8;
  float4 a = *(const float4*)(p);
  float4 b = *(const float4*)(p + 4);
  short8 o;
  o[0] = (short)f2b(a.x); o[1] = (short)f2b(a.y);
  o[2] = (short)f2b(a.z); o[3] = (short)f2b(a.w);
  o[4] = (short)f2b(b.x); o[5] = (short)f2b(b.y);
  o[6] = (short)f2b(b.z); o[7] = (short)f2b(b.w);
  *(short8*)(Xb + (size_t)i * 8) = o;
}

// ---------------- weight transpose + cast: W[K][N] f32 -> WT[N][K] bf16 ----
__global__ __launch_bounds__(256) void wtrans_k(const float* __restrict__ W,
                                                unsigned short* __restrict__ WT,
                                                int K, int N) {
  __shared__ float t[64][65];
  int k0 = blockIdx.x * 64, n0 = blockIdx.y * 64;
  for (int i = threadIdx.x; i < 4096; i += 256) {
    int r = i >> 6, c = i & 63;
    t[r][c] = W[(size_t)(k0 + r) * N + n0 + c];
  }
  __syncthreads();
  for (int i = threadIdx.x; i < 4096; i += 256) {
    int r = i >> 6, c = i & 63;
    WT[(size_t)(n0 + r) * K + k0 + c] = f2b(t[c][r]);
  }
}

// ---------------- V transpose (bf16): V[b*4096+s][h*64+d] -> Vt[(bh*64)+d][s] ----
__global__ __launch_bounds__(256) void vtrans_k(const unsigned short* __restrict__ V,
                                                unsigned short* __restrict__ Vt) {
  __shared__ unsigned short t[64][65];
  int s0 = blockIdx.x * 64;
  int bh = blockIdx.y;
  int b = bh >> 3, h = bh & 7;
  for (int i = threadIdx.x; i < 4096; i += 256) {
    int r = i >> 6, c = i & 63;
    t[r][c] = V[(size_t)(b * 4096 + s0 + r) * 512 + h * 64 + c];
  }
  __syncthreads();
  for (int i = threadIdx.x; i < 4096; i += 256) {
    int r = i >> 6, c = i & 63;  // output row = d, col = s
    Vt[(size_t)(bh * 64 + r) * 4096 + s0 + c] = t[c][r];
  }
}

// ---------------- GEMM: C[M][N] = A[M][K](bf16) * BT[N][K]^T(bf16) + bias ----
// EPI: 0 = f32 out, 1 = bf16 out, 2 = bf16 out + relu
template <int EPI>
__global__ __launch_bounds__(256) void gemm_bt(
    const unsigned short* __restrict__ A, const unsigned short* __restrict__ BT,
    const float* __restrict__ bias, float* __restrict__ Cf,
    unsigned short* __restrict__ Cb, int M, int N, int K) {
  __shared__ unsigned short As[128 * 32];
  __shared__ unsigned short Bs[128 * 32];
  int t = threadIdx.x, w = t >> 6, l = t & 63;
  int bm = blockIdx.x, bn = blockIdx.y;
  int wm = w >> 1, wn = w & 1;
  int g = l >> 4, ln = l & 15;
  f32x4 acc[4][4] = {};
  const unsigned short* Arow = A + (size_t)bm * 128 * K;
  const unsigned short* Brow = BT + (size_t)bn * 128 * K;
  int nk = K >> 5;
  for (int kt = 0; kt < nk; ++kt) {
    int k0 = kt * 32;
#pragma unroll
    for (int i = 0; i < 2; ++i) {
      int cl = i * 256 + t;
      int r = cl >> 2, c = cl & 3;
      char* ldsA = (char*)As + (size_t)(i * 256 + w * 64) * 16;
      char* ldsB = (char*)Bs + (size_t)(i * 256 + w * 64) * 16;
      gl16(Arow + (size_t)r * K + k0 + c * 8, ldsA);
      gl16(Brow + (size_t)r * K + k0 + c * 8, ldsB);
    }
    __syncthreads();
    short8 af[4], bf[4];
    int ko = g * 8;
#pragma unroll
    for (int i = 0; i < 4; ++i)
      af[i] = *(const short8*)&As[(wm * 64 + i * 16 + ln) * 32 + ko];
#pragma unroll
    for (int j = 0; j < 4; ++j)
      bf[j] = *(const short8*)&Bs[(wn * 64 + j * 16 + ln) * 32 + ko];
#pragma unroll
    for (int i = 0; i < 4; ++i)
#pragma unroll
      for (int j = 0; j < 4; ++j)
        acc[i][j] = __builtin_amdgcn_mfma_f32_16x16x32_bf16(af[i], bf[j], acc[i][j], 0, 0, 0);
    __syncthreads();
  }
#pragma unroll
  for (int i = 0; i < 4; ++i) {
    int row = bm * 128 + wm * 64 + i * 16 + g * 4;
#pragma unroll
    for (int j = 0; j < 4; ++j) {
      int col = bn * 128 + wn * 64 + j * 16 + ln;
      float bv = bias[col];
#pragma unroll
      for (int r = 0; r < 4; ++r) {
        float v = acc[i][j][r] + bv;
        if constexpr (EPI == 2) v = v > 0.f ? v : 0.f;
        if constexpr (EPI == 0) Cf[(size_t)(row + r) * N + col] = v;
        else Cb[(size_t)(row + r) * N + col] = f2b(v);
      }
    }
  }
}

// ---------------- flash attention ----------------
// grid (64 qtiles, 16 bh), 256 threads = 4 waves, each wave 16 q-rows.
__global__ __launch_bounds__(256) void attn_k(
    const unsigned short* __restrict__ Q, const unsigned short* __restrict__ Kb,
    const unsigned short* __restrict__ Vt, unsigned short* __restrict__ O) {
  __shared__ unsigned short Ks[64 * 64];
  __shared__ unsigned short Vs[64 * 64];
  __shared__ unsigned short Ps[64 * 64];  // 4 waves x [16][64]
  int t = threadIdx.x, w = t >> 6, l = t & 63;
  int qt = blockIdx.x, bh = blockIdx.y;
  int b = bh >> 3, h = bh & 7;
  int g = l >> 4, ln = l & 15;

  // Q fragments (scaled by 1/8), held in regs for the whole KV sweep
  short8 qf[2];
  size_t qrow = (size_t)(b * 4096 + qt * 64 + w * 16 + ln);
#pragma unroll
  for (int ks = 0; ks < 2; ++ks) {
    short8 v = *(const short8*)&Q[qrow * 512 + h * 64 + ks * 32 + g * 8];
#pragma unroll
    for (int j = 0; j < 8; ++j) v[j] = (short)f2b(b2f((unsigned short)v[j]) * 0.125f);
    qf[ks] = v;
  }

  f32x4 oacc[4] = {};
  float mreg[4], lreg[4];
#pragma unroll
  for (int r = 0; r < 4; ++r) { mreg[r] = -1e30f; lreg[r] = 0.f; }

  for (int kv = 0; kv < 4096; kv += 64) {
    // stage K tile [64 kk][64 d] and Vt tile [64 d][64 kk], XOR-swizzled source
#pragma unroll
    for (int i = 0; i < 2; ++i) {
      int cl = i * 256 + t;
      int r = cl >> 3, c = cl & 7;
      int cs = c ^ (r & 7);
      char* ldsK = (char*)Ks + (size_t)(i * 256 + w * 64) * 16;
      char* ldsV = (char*)Vs + (size_t)(i * 256 + w * 64) * 16;
      gl16(Kb + (size_t)(b * 4096 + kv + r) * 512 + h * 64 + cs * 8, ldsK);
      gl16(Vt + (size_t)(bh * 64 + r) * 4096 + kv + cs * 8, ldsV);
    }
    __syncthreads();

    // S = Q K^T  (4 kk-subtiles x 2 k-steps)
    f32x4 s[4];
#pragma unroll
    for (int tt = 0; tt < 4; ++tt) {
      s[tt] = (f32x4){0.f, 0.f, 0.f, 0.f};
#pragma unroll
      for (int ks = 0; ks < 2; ++ks) {
        int rr = tt * 16 + ln;
        int ch = ks * 4 + g;
        short8 kb = *(const short8*)((const char*)Ks + rr * 128 + ((ch ^ (rr & 7)) << 4));
        s[tt] = __builtin_amdgcn_mfma_f32_16x16x32_bf16(qf[ks], kb, s[tt], 0, 0, 0);
      }
    }

    // online softmax
    float mx[4], al[4], rs[4];
#pragma unroll
    for (int r = 0; r < 4; ++r) {
      mx[r] = fmaxf(fmaxf(s[0][r], s[1][r]), fmaxf(s[2][r], s[3][r]));
#pragma unroll
      for (int off = 1; off < 16; off <<= 1) mx[r] = fmaxf(mx[r], __shfl_xor(mx[r], off));
      float mn = fmaxf(mreg[r], mx[r]);
      al[r] = __builtin_amdgcn_exp2f((mreg[r] - mn) * LOG2E);
      mreg[r] = mn;
      lreg[r] *= al[r];
      rs[r] = 0.f;
    }
    // P = exp(S - m), write bf16 to swizzled LDS (per-wave region)
#pragma unroll
    for (int tt = 0; tt < 4; ++tt) {
#pragma unroll
      for (int r = 0; r < 4; ++r) {
        float p = __builtin_amdgcn_exp2f((s[tt][r] - mreg[r]) * LOG2E);
        rs[r] += p;
        int mq = g * 4 + r;
        int kk = tt * 16 + ln;
        int ch = kk >> 3;
        int byte = (w * 16 + mq) * 128 + ((ch ^ (mq & 7)) << 4) + (kk & 7) * 2;
        *(unsigned short*)((char*)Ps + byte) = f2b(p);
      }
    }
#pragma unroll
    for (int r = 0; r < 4; ++r) {
#pragma unroll
      for (int off = 1; off < 16; off <<= 1) rs[r] += __shfl_xor(rs[r], off);
      lreg[r] += rs[r];
    }
    // rescale O
#pragma unroll
    for (int dt = 0; dt < 4; ++dt)
#pragma unroll
      for (int r = 0; r < 4; ++r) oacc[dt][r] *= al[r];

    // PV: A = P (from LDS), B = Vt rows
    short8 pa[2];
#pragma unroll
    for (int ks = 0; ks < 2; ++ks) {
      int ch = ks * 4 + g;
      pa[ks] = *(const short8*)((const char*)Ps + (w * 16 + ln) * 128 + ((ch ^ (ln & 7)) << 4));
    }
#pragma unroll
    for (int dt = 0; dt < 4; ++dt) {
#pragma unroll
      for (int ks = 0; ks < 2; ++ks) {
        int rr = dt * 16 + ln;
        int ch = ks * 4 + g;
        short8 vb = *(const short8*)((const char*)Vs + rr * 128 + ((ch ^ (rr & 7)) << 4));
        oacc[dt] = __builtin_amdgcn_mfma_f32_16x16x32_bf16(pa[ks], vb, oacc[dt], 0, 0, 0);
      }
    }
    __syncthreads();
  }

  // write O (concat layout)
#pragma unroll
  for (int dt = 0; dt < 4; ++dt) {
#pragma unroll
    for (int r = 0; r < 4; ++r) {
      float v = oacc[dt][r] / lreg[r];
      size_t row = (size_t)(b * 4096 + qt * 64 + w * 16 + g * 4 + r);
      O[row * 512 + h * 64 + dt * 16 + ln] = f2b(v);
    }
  }
}

// ---------------- residual + LayerNorm (ddof=1, /(std+eps)) ----------------
template <bool WB>
__global__ __launch_bounds__(256) void ln_k(const float* __restrict__ X,
                                            const float* __restrict__ Y,
                                            const float* __restrict__ gamma,
                                            const float* __restrict__ beta,
                                            float* __restrict__ outf,
                                            unsigned short* __restrict__ outb) {
  int w = threadIdx.x >> 6, l = threadIdx.x & 63;
  size_t row = (size_t)blockIdx.x * 4 + w;
  const float* xr = X + row * 512;
  const float* yr = Y + row * 512;
  float vals[8];
  float s = 0.f, ss = 0.f;
#pragma unroll
  for (int i = 0; i < 2; ++i) {
    float4 a = *(const float4*)(xr + l * 8 + i * 4);
    float4 c = *(const float4*)(yr + l * 8 + i * 4);
    vals[i * 4 + 0] = a.x + c.x; vals[i * 4 + 1] = a.y + c.y;
    vals[i * 4 + 2] = a.z + c.z; vals[i * 4 + 3] = a.w + c.w;
  }
#pragma unroll
  for (int j = 0; j < 8; ++j) { s += vals[j]; ss += vals[j] * vals[j]; }
#pragma unroll
  for (int off = 1; off < 64; off <<= 1) { s += __shfl_xor(s, off); ss += __shfl_xor(ss, off); }
  float mean = s * (1.f / 512.f);
  float var = fmaxf((ss - 512.f * mean * mean) * (1.f / 511.f), 0.f);
  float inv = 1.f / (sqrtf(var) + 1e-6f);
  unsigned short bvals[8];
#pragma unroll
  for (int i = 0; i < 2; ++i) {
    float4 gm = *(const float4*)(gamma + l * 8 + i * 4);
    float4 bt = *(const float4*)(beta + l * 8 + i * 4);
    float4 o;
    o.x = gm.x * ((vals[i * 4 + 0] - mean) * inv) + bt.x;
    o.y = gm.y * ((vals[i * 4 + 1] - mean) * inv) + bt.y;
    o.z = gm.z * ((vals[i * 4 + 2] - mean) * inv) + bt.z;
    o.w = gm.w * ((vals[i * 4 + 3] - mean) * inv) + bt.w;
    *(float4*)(outf + row * 512 + l * 8 + i * 4) = o;
    if constexpr (WB) {
      bvals[i * 4 + 0] = f2b(o.x); bvals[i * 4 + 1] = f2b(o.y);
      bvals[i * 4 + 2] = f2b(o.z); bvals[i * 4 + 3] = f2b(o.w);
    }
  }
  if constexpr (WB) {
    short8 pk;
#pragma unroll
    for (int j = 0; j < 8; ++j) pk[j] = (short)bvals[j];
    *(short8*)(outb + row * 512 + l * 8) = pk;
  }
}

extern "C" void kernel_launch(void* const* d_in, const int* in_sizes, int n_in,
                              void* d_out, int out_size, void* d_ws, size_t ws_size,
                              hipStream_t stream) {
  const float* x  = (const float*)d_in[0];
  const float* Wq = (const float*)d_in[1];
  const float* bq = (const float*)d_in[2];
  const float* Wk = (const float*)d_in[3];
  const float* bk = (const float*)d_in[4];
  const float* Wv = (const float*)d_in[5];
  const float* bv = (const float*)d_in[6];
  const float* Wo = (const float*)d_in[7];
  const float* bo = (const float*)d_in[8];
  const float* a1 = (const float*)d_in[9];
  const float* b1 = (const float*)d_in[10];
  const float* a2 = (const float*)d_in[11];
  const float* b2 = (const float*)d_in[12];
  const float* W1 = (const float*)d_in[13];
  const float* c1 = (const float*)d_in[14];
  const float* W2 = (const float*)d_in[15];
  const float* c2 = (const float*)d_in[16];

  char* ws = (char*)d_ws;
  const size_t MB = 1024 * 1024;
  unsigned short* Xb  = (unsigned short*)(ws + 0);        // 8MB, later Att
  unsigned short* Qb  = (unsigned short*)(ws + 8 * MB);   // 8MB, later Y1b
  unsigned short* Kbf = (unsigned short*)(ws + 16 * MB);  // 8MB, later H lo
  unsigned short* Vb  = (unsigned short*)(ws + 24 * MB);  // 8MB, later H hi
  unsigned short* Vtb = (unsigned short*)(ws + 32 * MB);  // 8MB
  unsigned short* WqT = (unsigned short*)(ws + 40 * MB);
  unsigned short* WkT = (unsigned short*)(ws + 40 * MB + 512 * 1024);
  unsigned short* WvT = (unsigned short*)(ws + 41 * MB);
  unsigned short* WoT = (unsigned short*)(ws + 41 * MB + 512 * 1024);
  unsigned short* W1T = (unsigned short*)(ws + 42 * MB);
  unsigned short* W2T = (unsigned short*)(ws + 43 * MB);
  float* AO = (float*)(ws + 44 * MB);  // 16MB, later FFN out
  float* Y1 = (float*)(ws + 60 * MB);  // 16MB
  unsigned short* Att = Xb;
  unsigned short* Y1b = Qb;
  unsigned short* Hb  = Kbf;  // 16MB spanning Kbf+Vb

  castx_k<<<2048, 256, 0, stream>>>(x, Xb);
  wtrans_k<<<dim3(8, 8), 256, 0, stream>>>(Wq, WqT, 512, 512);
  wtrans_k<<<dim3(8, 8), 256, 0, stream>>>(Wk, WkT, 512, 512);
  wtrans_k<<<dim3(8, 8), 256, 0, stream>>>(Wv, WvT, 512, 512);
  wtrans_k<<<dim3(8, 8), 256, 0, stream>>>(Wo, WoT, 512, 512);
  wtrans_k<<<dim3(8, 16), 256, 0, stream>>>(W1, W1T, 512, 1024);
  wtrans_k<<<dim3(16, 8), 256, 0, stream>>>(W2, W2T, 1024, 512);

  gemm_bt<1><<<dim3(64, 4), 256, 0, stream>>>(Xb, WqT, bq, nullptr, Qb, 8192, 512, 512);
  gemm_bt<1><<<dim3(64, 4), 256, 0, stream>>>(Xb, WkT, bk, nullptr, Kbf, 8192, 512, 512);
  gemm_bt<1><<<dim3(64, 4), 256, 0, stream>>>(Xb, WvT, bv, nullptr, Vb, 8192, 512, 512);

  vtrans_k<<<dim3(64, 16), 256, 0, stream>>>(Vb, Vtb);
  attn_k<<<dim3(64, 16), 256, 0, stream>>>(Qb, Kbf, Vtb, Att);

  gemm_bt<0><<<dim3(64, 4), 256, 0, stream>>>(Att, WoT, bo, AO, nullptr, 8192, 512, 512);
  ln_k<true><<<2048, 256, 0, stream>>>(x, AO, a1, b1, Y1, Y1b);
  gemm_bt<2><<<dim3(64, 8), 256, 0, stream>>>(Y1b, W1T, c1, nullptr, Hb, 8192, 1024, 512);
  gemm_bt<0><<<dim3(64, 4), 256, 0, stream>>>(Hb, W2T, c2, AO, nullptr, 8192, 512, 1024);
  ln_k<false><<<2048, 256, 0, stream>>>(Y1, AO, a2, b2, (float*)d_out, nullptr);
}

// Round 3
// 270.992 us; speedup vs baseline: 1.3966x; 1.3966x over previous
//
#include <hip/hip_runtime.h>
#include <stdint.h>

typedef short short8 __attribute__((ext_vector_type(8)));
typedef float f32x4 __attribute__((ext_vector_type(4)));
typedef float f32x16 __attribute__((ext_vector_type(16)));
typedef unsigned int u32x4 __attribute__((ext_vector_type(4)));

#define LOG2E 1.44269504088896f

__device__ __forceinline__ unsigned short f2b(float f) {
  union { float f; unsigned int u; } x; x.f = f;
  unsigned int u = x.u;
  unsigned int r = (u + 0x7fffu + ((u >> 16) & 1u)) >> 16;
  return (unsigned short)r;
}
__device__ __forceinline__ float b2f(unsigned short s) {
  union { unsigned int u; float f; } x; x.u = ((unsigned int)s) << 16;
  return x.f;
}
__device__ __forceinline__ void gl16(const void* g, void* l) {
  __builtin_amdgcn_global_load_lds((const __attribute__((address_space(1))) void*)g,
                                   (__attribute__((address_space(3))) void*)l, 16, 0, 0);
}
__device__ __forceinline__ unsigned int cvtpk(float lo, float hi) {
  unsigned int r;
  asm("v_cvt_pk_bf16_f32 %0, %1, %2" : "=v"(r) : "v"(lo), "v"(hi));
  return r;
}
__device__ __forceinline__ void plswap(unsigned int& a, unsigned int& b) {
  asm volatile("v_permlane32_swap_b32 %0, %1" : "+v"(a), "+v"(b));
}

// ---------------- cast x -> bf16 ----------------
__global__ __launch_bounds__(256) void castx_k(const float* __restrict__ X,
                                               unsigned short* __restrict__ Xb) {
  int i = blockIdx.x * 256 + threadIdx.x;  // one thread = 8 elems
  const float* p = X + (size_t)i * 8;
  float4 a = *(const float4*)(p);
  float4 b = *(const float4*)(p + 4);
  short8 o;
  o[0] = (short)f2b(a.x); o[1] = (short)f2b(a.y);
  o[2] = (short)f2b(a.z); o[3] = (short)f2b(a.w);
  o[4] = (short)f2b(b.x); o[5] = (short)f2b(b.y);
  o[6] = (short)f2b(b.z); o[7] = (short)f2b(b.w);
  *(short8*)(Xb + (size_t)i * 8) = o;
}

// ---------------- weight transpose + cast: W[K][N] f32 -> WT[N][K] bf16 ----
__global__ __launch_bounds__(256) void wtrans_k(const float* __restrict__ W,
                                                unsigned short* __restrict__ WT,
                                                int K, int N) {
  __shared__ float t[64][65];
  int k0 = blockIdx.x * 64, n0 = blockIdx.y * 64;
  for (int i = threadIdx.x; i < 4096; i += 256) {
    int r = i >> 6, c = i & 63;
    t[r][c] = W[(size_t)(k0 + r) * N + n0 + c];
  }
  __syncthreads();
  for (int i = threadIdx.x; i < 4096; i += 256) {
    int r = i >> 6, c = i & 63;
    WT[(size_t)(n0 + r) * K + k0 + c] = f2b(t[c][r]);
  }
}

// ---------------- V transpose (bf16): V[b*4096+s][h*64+d] -> Vt[(bh*64)+d][s] ----
__global__ __launch_bounds__(256) void vtrans_k(const unsigned short* __restrict__ V,
                                                unsigned short* __restrict__ Vt) {
  __shared__ unsigned short t[64][65];
  int s0 = blockIdx.x * 64;
  int bh = blockIdx.y;
  int b = bh >> 3, h = bh & 7;
  for (int i = threadIdx.x; i < 4096; i += 256) {
    int r = i >> 6, c = i & 63;
    t[r][c] = V[(size_t)(b * 4096 + s0 + r) * 512 + h * 64 + c];
  }
  __syncthreads();
  for (int i = threadIdx.x; i < 4096; i += 256) {
    int r = i >> 6, c = i & 63;  // output row = d, col = s
    Vt[(size_t)(bh * 64 + r) * 4096 + s0 + c] = t[c][r];
  }
}

// ---------------- GEMM: C[M][N] = A[M][K](bf16) * BT[N][K]^T(bf16) + bias ----
// EPI: 0 = f32 out, 1 = bf16 out, 2 = bf16 out + relu
template <int EPI>
__global__ __launch_bounds__(256) void gemm_bt(
    const unsigned short* __restrict__ A, const unsigned short* __restrict__ BT,
    const float* __restrict__ bias, float* __restrict__ Cf,
    unsigned short* __restrict__ Cb, int M, int N, int K) {
  __shared__ unsigned short As[128 * 32];
  __shared__ unsigned short Bs[128 * 32];
  int t = threadIdx.x, w = t >> 6, l = t & 63;
  int bm = blockIdx.x, bn = blockIdx.y;
  int wm = w >> 1, wn = w & 1;
  int g = l >> 4, ln = l & 15;
  f32x4 acc[4][4] = {};
  const unsigned short* Arow = A + (size_t)bm * 128 * K;
  const unsigned short* Brow = BT + (size_t)bn * 128 * K;
  int nk = K >> 5;
  for (int kt = 0; kt < nk; ++kt) {
    int k0 = kt * 32;
#pragma unroll
    for (int i = 0; i < 2; ++i) {
      int cl = i * 256 + t;
      int r = cl >> 2, c = cl & 3;
      char* ldsA = (char*)As + (size_t)(i * 256 + w * 64) * 16;
      char* ldsB = (char*)Bs + (size_t)(i * 256 + w * 64) * 16;
      gl16(Arow + (size_t)r * K + k0 + c * 8, ldsA);
      gl16(Brow + (size_t)r * K + k0 + c * 8, ldsB);
    }
    __syncthreads();
    short8 af[4], bf[4];
    int ko = g * 8;
#pragma unroll
    for (int i = 0; i < 4; ++i)
      af[i] = *(const short8*)&As[(wm * 64 + i * 16 + ln) * 32 + ko];
#pragma unroll
    for (int j = 0; j < 4; ++j)
      bf[j] = *(const short8*)&Bs[(wn * 64 + j * 16 + ln) * 32 + ko];
#pragma unroll
    for (int i = 0; i < 4; ++i)
#pragma unroll
      for (int j = 0; j < 4; ++j)
        acc[i][j] = __builtin_amdgcn_mfma_f32_16x16x32_bf16(af[i], bf[j], acc[i][j], 0, 0, 0);
    __syncthreads();
  }
#pragma unroll
  for (int i = 0; i < 4; ++i) {
    int row = bm * 128 + wm * 64 + i * 16 + g * 4;
#pragma unroll
    for (int j = 0; j < 4; ++j) {
      int col = bn * 128 + wn * 64 + j * 16 + ln;
      float bv = bias[col];
#pragma unroll
      for (int r = 0; r < 4; ++r) {
        float v = acc[i][j][r] + bv;
        if constexpr (EPI == 2) v = v > 0.f ? v : 0.f;
        if constexpr (EPI == 0) Cf[(size_t)(row + r) * N + col] = v;
        else Cb[(size_t)(row + r) * N + col] = f2b(v);
      }
    }
  }
}

// ---------------- flash attention, swapped-operand 32x32 structure ----------
// grid (32 q-blocks of 128, 16 bh), 256 threads = 4 waves, each wave 32 q-rows.
// S^T = mfma(K, Q): col=lane&31 = q  -> per-lane softmax state.
// O^T = mfma(Vt, P): col=lane&31 = q -> per-lane rescale.
__global__ __launch_bounds__(256) void attn_k(
    const unsigned short* __restrict__ Q, const unsigned short* __restrict__ Kb,
    const unsigned short* __restrict__ Vt, unsigned short* __restrict__ O) {
  __shared__ unsigned short Ks[2][4096];
  __shared__ unsigned short Vs[2][4096];
  int tid = threadIdx.x, wv = tid >> 6, lane = tid & 63;
  int l31 = lane & 31, hi = lane >> 5;
  int qb = blockIdx.x, bh = blockIdx.y;
  int b = bh >> 3, h = bh & 7;
  int q0 = qb * 128 + wv * 32;  // warp's q base within sequence

  // Q B-fragments: qf[ks] holds Q[q0+l31][ks*16 + hi*8 + j] * 0.125 (exact pow2)
  short8 qf[4];
  {
    const unsigned short* qp = Q + (size_t)(b * 4096 + q0 + l31) * 512 + h * 64;
#pragma unroll
    for (int ks = 0; ks < 4; ++ks) {
      short8 v = *(const short8*)(qp + ks * 16 + hi * 8);
#pragma unroll
      for (int j = 0; j < 8; ++j) v[j] = (short)f2b(b2f((unsigned short)v[j]) * 0.125f);
      qf[ks] = v;
    }
  }

  f32x16 o0 = {}, o1 = {};
  float m = -1e30f, lsum = 0.f;
  int swcol = ((lane & 7) ^ (lane >> 3)) * 8;  // pre-swizzled global col (r&7 == lane>>3)
  int rsw = (l31 & 7) << 4;                    // read-side swizzle

  auto stage = [&](int buf, int kv) {
    const unsigned short* ksrc = Kb + (size_t)(b * 4096 + kv) * 512 + h * 64;
    const unsigned short* vsrc = Vt + (size_t)(bh * 64) * 4096 + kv;
#pragma unroll
    for (int i = 0; i < 2; ++i) {
      int r = wv * 16 + i * 8 + (lane >> 3);
      gl16(ksrc + (size_t)r * 512 + swcol, (char*)&Ks[buf][0] + wv * 2048 + i * 1024);
      gl16(vsrc + (size_t)r * 4096 + swcol, (char*)&Vs[buf][0] + wv * 2048 + i * 1024);
    }
  };

  stage(0, 0);
  __syncthreads();
  int buf = 0;
  for (int t = 0; t < 64; ++t) {
    if (t < 63) stage(buf ^ 1, (t + 1) * 64);

    // ---- S^T[kk][q] = K · Q^T : 2 kk-subtiles x 4 k-steps ----
    f32x16 s0 = {}, s1 = {};
    const char* kbase = (const char*)&Ks[buf][0];
#pragma unroll
    for (int ks = 0; ks < 4; ++ks) {
      int cb = ks * 32 + hi * 16;
      short8 k0 = *(const short8*)(kbase + l31 * 128 + (cb ^ rsw));
      short8 k1 = *(const short8*)(kbase + (l31 + 32) * 128 + (cb ^ rsw));
      s0 = __builtin_amdgcn_mfma_f32_32x32x16_bf16(k0, qf[ks], s0, 0, 0, 0);
      s1 = __builtin_amdgcn_mfma_f32_32x32x16_bf16(k1, qf[ks], s1, 0, 0, 0);
    }

    // ---- per-lane row max (tree) + partner-half ----
    float tm[8];
#pragma unroll
    for (int r = 0; r < 8; ++r)
      tm[r] = fmaxf(fmaxf(s0[r], s0[r + 8]), fmaxf(s1[r], s1[r + 8]));
#pragma unroll
    for (int r = 0; r < 4; ++r) tm[r] = fmaxf(tm[r], tm[r + 4]);
    float px = fmaxf(fmaxf(tm[0], tm[1]), fmaxf(tm[2], tm[3]));
    px = fmaxf(px, __shfl_xor(px, 32));

    // ---- defer-max rescale (T13) ----
    if (__any(px - m > 8.0f)) {
      float mn = fmaxf(m, px);
      float al = __builtin_amdgcn_exp2f((m - mn) * LOG2E);
      m = mn;
      lsum *= al;
#pragma unroll
      for (int r = 0; r < 16; ++r) { o0[r] *= al; o1[r] *= al; }
    }

    // ---- P = exp(S - m) in place, partial sums ----
    float negm = -m * LOG2E;
    float rsv[4] = {0.f, 0.f, 0.f, 0.f};
#pragma unroll
    for (int r = 0; r < 16; ++r) {
      float p = __builtin_amdgcn_exp2f(fmaf(s0[r], LOG2E, negm));
      s0[r] = p; rsv[r & 3] += p;
    }
#pragma unroll
    for (int r = 0; r < 16; ++r) {
      float p = __builtin_amdgcn_exp2f(fmaf(s1[r], LOG2E, negm));
      s1[r] = p; rsv[r & 3] += p;
    }
    float rs = (rsv[0] + rsv[1]) + (rsv[2] + rsv[3]);
    rs += __shfl_xor(rs, 32);
    lsum += rs;

    // ---- pack P -> PV B-fragments (cvt_pk + permlane32_swap, T12) ----
    short8 pf[4];
    {
      unsigned int u0 = cvtpk(s0[0], s0[1]), u1 = cvtpk(s0[4], s0[5]);
      plswap(u0, u1);
      unsigned int u2 = cvtpk(s0[2], s0[3]), u3 = cvtpk(s0[6], s0[7]);
      plswap(u2, u3);
      unsigned int u4 = cvtpk(s0[8], s0[9]), u5 = cvtpk(s0[12], s0[13]);
      plswap(u4, u5);
      unsigned int u6 = cvtpk(s0[10], s0[11]), u7 = cvtpk(s0[14], s0[15]);
      plswap(u6, u7);
      union { u32x4 u; short8 s; } cv;
      cv.u = (u32x4){u0, u2, u1, u3}; pf[0] = cv.s;
      cv.u = (u32x4){u4, u6, u5, u7}; pf[1] = cv.s;
      unsigned int w0 = cvtpk(s1[0], s1[1]), w1 = cvtpk(s1[4], s1[5]);
      plswap(w0, w1);
      unsigned int w2 = cvtpk(s1[2], s1[3]), w3 = cvtpk(s1[6], s1[7]);
      plswap(w2, w3);
      unsigned int w4 = cvtpk(s1[8], s1[9]), w5 = cvtpk(s1[12], s1[13]);
      plswap(w4, w5);
      unsigned int w6 = cvtpk(s1[10], s1[11]), w7 = cvtpk(s1[14], s1[15]);
      plswap(w6, w7);
      cv.u = (u32x4){w0, w2, w1, w3}; pf[2] = cv.s;
      cv.u = (u32x4){w4, w6, w5, w7}; pf[3] = cv.s;
    }

    // ---- O^T += Vt · P : 2 d-subtiles x 4 k-steps ----
    const char* vbase = (const char*)&Vs[buf][0];
#pragma unroll
    for (int ks = 0; ks < 4; ++ks) {
      int cb = ks * 32 + hi * 16;
      short8 v0 = *(const short8*)(vbase + l31 * 128 + (cb ^ rsw));
      short8 v1 = *(const short8*)(vbase + (l31 + 32) * 128 + (cb ^ rsw));
      o0 = __builtin_amdgcn_mfma_f32_32x32x16_bf16(v0, pf[ks], o0, 0, 0, 0);
      o1 = __builtin_amdgcn_mfma_f32_32x32x16_bf16(v1, pf[ks], o1, 0, 0, 0);
    }
    __syncthreads();
    buf ^= 1;
  }

  // ---- epilogue: O^T regs -> LDS (swizzled) -> coalesced global ----
  float linv = 1.0f / lsum;
  unsigned short* ep = &Ks[0][0] + wv * 2048;  // 4KB per warp
#pragma unroll
  for (int r = 0; r < 16; r += 2) {
    int d0 = (r & 3) + 8 * (r >> 2) + 4 * hi;
    unsigned int pk0 = cvtpk(o0[r] * linv, o0[r + 1] * linv);
    unsigned int pk1 = cvtpk(o1[r] * linv, o1[r + 1] * linv);
    *(unsigned int*)((char*)ep + l31 * 128 + ((2 * d0) ^ ((l31 & 7) << 4))) = pk0;
    *(unsigned int*)((char*)ep + l31 * 128 + ((2 * (d0 + 32)) ^ ((l31 & 7) << 4))) = pk1;
  }
#pragma unroll
  for (int pass = 0; pass < 4; ++pass) {
    int q = pass * 8 + (lane >> 3);
    // read chunk (lane&7)^(q&7) of row q -> after the write-side swizzle this
    // holds d-group (lane&7) already de-swizzled; store LINEAR.
    short8 v = *(const short8*)((char*)ep + q * 128 + (((lane & 7) * 16) ^ ((q & 7) << 4)));
    size_t row = (size_t)(b * 4096 + q0 + q);
    *(short8*)(O + row * 512 + h * 64 + (lane & 7) * 8) = v;
  }
}

// ---------------- residual + LayerNorm (ddof=1, /(std+eps)) ----------------
template <bool WB>
__global__ __launch_bounds__(256) void ln_k(const float* __restrict__ X,
                                            const float* __restrict__ Y,
                                            const float* __restrict__ gamma,
                                            const float* __restrict__ beta,
                                            float* __restrict__ outf,
                                            unsigned short* __restrict__ outb) {
  int w = threadIdx.x >> 6, l = threadIdx.x & 63;
  size_t row = (size_t)blockIdx.x * 4 + w;
  const float* xr = X + row * 512;
  const float* yr = Y + row * 512;
  float vals[8];
  float s = 0.f, ss = 0.f;
#pragma unroll
  for (int i = 0; i < 2; ++i) {
    float4 a = *(const float4*)(xr + l * 8 + i * 4);
    float4 c = *(const float4*)(yr + l * 8 + i * 4);
    vals[i * 4 + 0] = a.x + c.x; vals[i * 4 + 1] = a.y + c.y;
    vals[i * 4 + 2] = a.z + c.z; vals[i * 4 + 3] = a.w + c.w;
  }
#pragma unroll
  for (int j = 0; j < 8; ++j) { s += vals[j]; ss += vals[j] * vals[j]; }
#pragma unroll
  for (int off = 1; off < 64; off <<= 1) { s += __shfl_xor(s, off); ss += __shfl_xor(ss, off); }
  float mean = s * (1.f / 512.f);
  float var = fmaxf((ss - 512.f * mean * mean) * (1.f / 511.f), 0.f);
  float inv = 1.f / (sqrtf(var) + 1e-6f);
  unsigned short bvals[8];
#pragma unroll
  for (int i = 0; i < 2; ++i) {
    float4 gm = *(const float4*)(gamma + l * 8 + i * 4);
    float4 bt = *(const float4*)(beta + l * 8 + i * 4);
    float4 o;
    o.x = gm.x * ((vals[i * 4 + 0] - mean) * inv) + bt.x;
    o.y = gm.y * ((vals[i * 4 + 1] - mean) * inv) + bt.y;
    o.z = gm.z * ((vals[i * 4 + 2] - mean) * inv) + bt.z;
    o.w = gm.w * ((vals[i * 4 + 3] - mean) * inv) + bt.w;
    *(float4*)(outf + row * 512 + l * 8 + i * 4) = o;
    if constexpr (WB) {
      bvals[i * 4 + 0] = f2b(o.x); bvals[i * 4 + 1] = f2b(o.y);
      bvals[i * 4 + 2] = f2b(o.z); bvals[i * 4 + 3] = f2b(o.w);
    }
  }
  if constexpr (WB) {
    short8 pk;
#pragma unroll
    for (int j = 0; j < 8; ++j) pk[j] = (short)bvals[j];
    *(short8*)(outb + row * 512 + l * 8) = pk;
  }
}

extern "C" void kernel_launch(void* const* d_in, const int* in_sizes, int n_in,
                              void* d_out, int out_size, void* d_ws, size_t ws_size,
                              hipStream_t stream) {
  const float* x  = (const float*)d_in[0];
  const float* Wq = (const float*)d_in[1];
  const float* bq = (const float*)d_in[2];
  const float* Wk = (const float*)d_in[3];
  const float* bk = (const float*)d_in[4];
  const float* Wv = (const float*)d_in[5];
  const float* bv = (const float*)d_in[6];
  const float* Wo = (const float*)d_in[7];
  const float* bo = (const float*)d_in[8];
  const float* a1 = (const float*)d_in[9];
  const float* b1 = (const float*)d_in[10];
  const float* a2 = (const float*)d_in[11];
  const float* b2 = (const float*)d_in[12];
  const float* W1 = (const float*)d_in[13];
  const float* c1 = (const float*)d_in[14];
  const float* W2 = (const float*)d_in[15];
  const float* c2 = (const float*)d_in[16];

  char* ws = (char*)d_ws;
  const size_t MB = 1024 * 1024;
  unsigned short* Xb  = (unsigned short*)(ws + 0);        // 8MB, later Att
  unsigned short* Qb  = (unsigned short*)(ws + 8 * MB);   // 8MB, later Y1b
  unsigned short* Kbf = (unsigned short*)(ws + 16 * MB);  // 8MB, later H lo
  unsigned short* Vb  = (unsigned short*)(ws + 24 * MB);  // 8MB, later H hi
  unsigned short* Vtb = (unsigned short*)(ws + 32 * MB);  // 8MB
  unsigned short* WqT = (unsigned short*)(ws + 40 * MB);
  unsigned short* WkT = (unsigned short*)(ws + 40 * MB + 512 * 1024);
  unsigned short* WvT = (unsigned short*)(ws + 41 * MB);
  unsigned short* WoT = (unsigned short*)(ws + 41 * MB + 512 * 1024);
  unsigned short* W1T = (unsigned short*)(ws + 42 * MB);
  unsigned short* W2T = (unsigned short*)(ws + 43 * MB);
  float* AO = (float*)(ws + 44 * MB);  // 16MB, later FFN out
  float* Y1 = (float*)(ws + 60 * MB);  // 16MB
  unsigned short* Att = Xb;
  unsigned short* Y1b = Qb;
  unsigned short* Hb  = Kbf;  // 16MB spanning Kbf+Vb

  castx_k<<<2048, 256, 0, stream>>>(x, Xb);
  wtrans_k<<<dim3(8, 8), 256, 0, stream>>>(Wq, WqT, 512, 512);
  wtrans_k<<<dim3(8, 8), 256, 0, stream>>>(Wk, WkT, 512, 512);
  wtrans_k<<<dim3(8, 8), 256, 0, stream>>>(Wv, WvT, 512, 512);
  wtrans_k<<<dim3(8, 8), 256, 0, stream>>>(Wo, WoT, 512, 512);
  wtrans_k<<<dim3(8, 16), 256, 0, stream>>>(W1, W1T, 512, 1024);
  wtrans_k<<<dim3(16, 8), 256, 0, stream>>>(W2, W2T, 1024, 512);

  gemm_bt<1><<<dim3(64, 4), 256, 0, stream>>>(Xb, WqT, bq, nullptr, Qb, 8192, 512, 512);
  gemm_bt<1><<<dim3(64, 4), 256, 0, stream>>>(Xb, WkT, bk, nullptr, Kbf, 8192, 512, 512);
  gemm_bt<1><<<dim3(64, 4), 256, 0, stream>>>(Xb, WvT, bv, nullptr, Vb, 8192, 512, 512);

  vtrans_k<<<dim3(64, 16), 256, 0, stream>>>(Vb, Vtb);
  attn_k<<<dim3(32, 16), 256, 0, stream>>>(Qb, Kbf, Vtb, Att);

  gemm_bt<0><<<dim3(64, 4), 256, 0, stream>>>(Att, WoT, bo, AO, nullptr, 8192, 512, 512);
  ln_k<true><<<2048, 256, 0, stream>>>(x, AO, a1, b1, Y1, Y1b);
  gemm_bt<2><<<dim3(64, 8), 256, 0, stream>>>(Y1b, W1T, c1, nullptr, Hb, 8192, 1024, 512);
  gemm_bt<0><<<dim3(64, 4), 256, 0, stream>>>(Hb, W2T, c2, AO, nullptr, 8192, 512, 1024);
  ln_k<false><<<2048, 256, 0, stream>>>(Y1, AO, a2, b2, (float*)d_out, nullptr);
}